// Round 13
// baseline (111.669 us; speedup 1.0000x reference)
//
#include <hip/hip_runtime.h>

// Attention 8192x8192, D=DV=64, fp32 in/out.
// R13: barrier-free 4-waves/SIMD. V tiles staged via wave-private
// global_load_lds DMA (double-buffered per-wave LDS regions) guarded by
// manual s_waitcnt vmcnt(8) — no __syncthreads in the K-loop. K fragments in
// ping-pong VGPRs. 16 waves = 2 row-halves x 8 key-chunks, 1024-thr blocks,
// grid 256 (128 rg x 2 kh). 8 XCD-local copies of the fragment-linear bf16
// K/Vt (prepass writes copy blockIdx%8; main reads copy blockIdx%8) cut frag
// latency and spread L2 load. Fixed-offset softmax, truncation P pack,
// (O,l) partials + merge kernel.

#define NQ 8192
#define NK 8192

typedef float f32x4 __attribute__((ext_vector_type(4)));
typedef short short8 __attribute__((ext_vector_type(8)));
union U4 { uint4 u; short8 s; };

#define MFMA16 __builtin_amdgcn_mfma_f32_16x16x32_bf16

// round-to-nearest-even fp32->bf16 pair pack (lo = a) — prepass/Q only
__device__ __forceinline__ unsigned pk2(float a, float b) {
    unsigned ua = __builtin_bit_cast(unsigned, a);
    unsigned ub = __builtin_bit_cast(unsigned, b);
    ua = (ua + 0x7FFFu + ((ua >> 16) & 1u)) >> 16;
    ub = (ub + 0x7FFFu + ((ub >> 16) & 1u)) & 0xFFFF0000u;
    return ua | ub;
}

// 1-op truncation pack: dst = {hi16(b), hi16(a)} (lo = a)
__device__ __forceinline__ unsigned pkt(float a, float b) {
    return __builtin_amdgcn_perm(__builtin_bit_cast(unsigned, b),
                                 __builtin_bit_cast(unsigned, a), 0x07060302u);
}

// async 16B/lane global->LDS (lands at ldsbase + lane*16) — verified in R12
__device__ __forceinline__ void async16(const uint4* g, uint4* l) {
    __builtin_amdgcn_global_load_lds(
        (const __attribute__((address_space(1))) void*)g,
        (__attribute__((address_space(3))) void*)l, 16, 0, 0);
}

// ---- prepass: 8 XCD-local copies of fragment-linear bf16 K / Vt ----
// grid 4096: copy = blockIdx%8 (lands on XCD blockIdx%8), j = blockIdx/8:
// j<256 -> K chunk j; else V chunk j-256.
__global__ __launch_bounds__(256)
void prepass(const float* __restrict__ Kg, const float* __restrict__ Vg,
             uint4* __restrict__ Kb4, uint4* __restrict__ Vt4) {
    __shared__ float ld[64 * 33];
    const int t = threadIdx.x, b = blockIdx.x;
    const int copy = b & 7, j = b >> 3;
    uint4* Kc = Kb4 + (size_t)copy * 65536;
    uint4* Vc = Vt4 + (size_t)copy * 65536;

    if (j < 256) {
        const int kl = t >> 3, dg = t & 7;
        const int e = kl & 1, i16 = kl >> 1, h = dg >> 2, q = dg & 3;
        const float* gp = Kg + (size_t)(j * 32 + kl) * 64 + dg * 8;
        float4 f0 = *(const float4*)gp;
        float4 f1 = *(const float4*)(gp + 4);
        uint4 o = make_uint4(pk2(f0.x, f0.y), pk2(f0.z, f0.w),
                             pk2(f1.x, f1.y), pk2(f1.z, f1.w));
        Kc[(size_t)(j * 4 + e * 2 + h) * 64 + i16 * 4 + q] = o;
    } else {
        const int c = j - 256;
        {
            const int key = t >> 3, dg = t & 7;
            const float* gp = Vg + (size_t)(c * 32 + key) * 64 + dg * 8;
            float4 f0 = *(const float4*)gp;
            float4 f1 = *(const float4*)(gp + 4);
            ld[(dg * 8 + 0) * 33 + key] = f0.x;
            ld[(dg * 8 + 1) * 33 + key] = f0.y;
            ld[(dg * 8 + 2) * 33 + key] = f0.z;
            ld[(dg * 8 + 3) * 33 + key] = f0.w;
            ld[(dg * 8 + 4) * 33 + key] = f1.x;
            ld[(dg * 8 + 5) * 33 + key] = f1.y;
            ld[(dg * 8 + 6) * 33 + key] = f1.z;
            ld[(dg * 8 + 7) * 33 + key] = f1.w;
        }
        __syncthreads();
        {
            const int dim = t >> 2, kq = t & 3;
            const int dt = dim >> 4, i16 = dim & 15;
            float v[8];
            #pragma unroll
            for (int jj = 0; jj < 8; ++jj) v[jj] = ld[dim * 33 + kq * 8 + jj];
            uint4 o = make_uint4(pk2(v[0], v[1]), pk2(v[2], v[3]),
                                 pk2(v[4], v[5]), pk2(v[6], v[7]));
            Vc[(size_t)(c * 4 + dt) * 64 + i16 * 4 + kq] = o;
        }
    }
}

// ---- main kernel: 64 rows x 4096 keys per block, writes (O,l) partials ----
__global__ __launch_bounds__(1024)
void attn_main(const float* __restrict__ Qg,
               const uint4* __restrict__ Kb4,
               const uint4* __restrict__ Vt4,
               float* __restrict__ Opart,
               float* __restrict__ Lpart) {
    // LDS (uint4 units): [0,4096) V buf0 (16 waves x 256), [4096,8192) V buf1,
    // [8192,10240) P regions [(w*2+rt)] x 64.  Total 160 KB.
    // Merge phase aliases 8 regions x 2080 floats from offset 0 (post-sync).
    __shared__ uint4 shb4[10240];
    float* sF = (float*)shb4;
    unsigned* shu = (unsigned*)shb4;

    const int t = threadIdx.x, w = t >> 6, lane = t & 63;
    const int q = lane >> 4, i16 = lane & 15;
    const int rh = w >> 3;           // row-half 0/1
    const int kc = w & 7;            // key-chunk within tile
    const int bid = blockIdx.x;
    const int kh = bid & 1;          // key half 0/1
    const int rg = bid >> 1;         // row group 0..127
    const int qb0 = rg * 64;
    const int lsl = i16 * 4 + q;     // lane-linear slot (0..63)
    const int phase = rg & 15;       // tile-order rotation (16 tiles)
    const uint4* Kb = Kb4 + (size_t)(bid & 7) * 65536;   // XCD-local copy
    const uint4* Vt = Vt4 + (size_t)(bid & 7) * 65536;

    // Q fragments: 2 row-tiles for this wave's row-half (scale 1/8*log2e)
    const float SCL = 0.18033688011112042f;
    short8 aq[2][2];
    #pragma unroll
    for (int rt = 0; rt < 2; ++rt) {
        const float* qp = Qg + (size_t)(qb0 + rh * 32 + rt * 16 + i16) * 64 + q * 8;
        float4 f0 = *(const float4*)(qp);
        float4 f1 = *(const float4*)(qp + 4);
        U4 u;
        u.u = make_uint4(pk2(f0.x * SCL, f0.y * SCL), pk2(f0.z * SCL, f0.w * SCL),
                         pk2(f1.x * SCL, f1.y * SCL), pk2(f1.z * SCL, f1.w * SCL));
        aq[rt][0] = u.s;
        f0 = *(const float4*)(qp + 32);
        f1 = *(const float4*)(qp + 36);
        u.u = make_uint4(pk2(f0.x * SCL, f0.y * SCL), pk2(f0.z * SCL, f0.w * SCL),
                         pk2(f1.x * SCL, f1.y * SCL), pk2(f1.z * SCL, f1.w * SCL));
        aq[rt][1] = u.s;
    }

    f32x4 acc[2][4];           // O partial accumulators (AGPR), static idx
    float lsum[2][4];          // per-lane row-sum partials (VALU)
    #pragma unroll
    for (int rt = 0; rt < 2; ++rt) {
        #pragma unroll
        for (int dt = 0; dt < 4; ++dt) { acc[rt][dt][0]=0.f; acc[rt][dt][1]=0.f; acc[rt][dt][2]=0.f; acc[rt][dt][3]=0.f; }
        #pragma unroll
        for (int r = 0; r < 4; ++r) lsum[rt][r] = 0.f;
    }

    // P slot indices (layout verified in R2-R12)
    const int tpw = ((i16 >> 2) & 1) + 2 * q + 32 * (i16 >> 3);  // tp = tpw + 8r
    const int pp  = i16 & 3;
    const int tpr = (q & 1) + 2 * ((i16 >> 2) & 3) + 8 * (i16 & 3) + 32 * (q >> 1);

    uint4 kfA[4], kfB[4];

    // wave-private V DMA: tile TT -> LDS buf B region of this wave
#define DMA_V(TT, B)                                                          \
    do {                                                                      \
        const int cg = (kh << 7) + ((((TT) + phase) & 15) * 8 + kc);          \
        _Pragma("unroll")                                                     \
        for (int dt = 0; dt < 4; ++dt)                                        \
            async16(Vt + (size_t)(cg * 4 + dt) * 64 + lane,                   \
                    shb4 + (B) * 4096 + w * 256 + dt * 64);                   \
    } while (0)

#define LOADK(TT, KD)                                                         \
    do {                                                                      \
        const int cg = (kh << 7) + ((((TT) + phase) & 15) * 8 + kc);          \
        _Pragma("unroll")                                                     \
        for (int eh = 0; eh < 4; ++eh)                                        \
            (KD)[eh] = Kb[(size_t)(cg * 4 + eh) * 64 + lsl];                  \
    } while (0)

    // QK^T -> exp2 -> pack P into this wave's P region
#define QKEXP(KD)                                                             \
    do {                                                                      \
        U4 u0, u1, u2, u3;                                                    \
        u0.u = (KD)[0]; u1.u = (KD)[1]; u2.u = (KD)[2]; u3.u = (KD)[3];       \
        _Pragma("unroll")                                                     \
        for (int rt = 0; rt < 2; ++rt) {                                      \
            f32x4 s0, s1;                                                     \
            s0[0]=-16.f; s0[1]=-16.f; s0[2]=-16.f; s0[3]=-16.f;               \
            s1[0]=-16.f; s1[1]=-16.f; s1[2]=-16.f; s1[3]=-16.f;               \
            s0 = MFMA16(aq[rt][0], u0.s, s0, 0, 0, 0);                        \
            s0 = MFMA16(aq[rt][1], u1.s, s0, 0, 0, 0);                        \
            s1 = MFMA16(aq[rt][0], u2.s, s1, 0, 0, 0);                        \
            s1 = MFMA16(aq[rt][1], u3.s, s1, 0, 0, 0);                        \
            const int rbase = (8192 + (w * 2 + rt) * 64) * 4;                 \
            _Pragma("unroll")                                                 \
            for (int r = 0; r < 4; ++r) {                                     \
                float p0 = __builtin_amdgcn_exp2f(s0[r]);                     \
                float p1 = __builtin_amdgcn_exp2f(s1[r]);                     \
                lsum[rt][r] += p0;                                            \
                lsum[rt][r] += p1;                                            \
                shu[rbase + (tpw + 8 * r) * 4 + pp] = pkt(p0, p1);            \
            }                                                                 \
        }                                                                     \
    } while (0)

    // P A-frags (lgkm in-order drains the just-issued P writes) + V from buf B
#define PVS(B)                                                                \
    do {                                                                      \
        U4 ap0, ap1;                                                          \
        ap0.u = shb4[8192 + (w * 2 + 0) * 64 + tpr];                          \
        ap1.u = shb4[8192 + (w * 2 + 1) * 64 + tpr];                          \
        _Pragma("unroll")                                                     \
        for (int dt = 0; dt < 4; ++dt) {                                      \
            U4 bv; bv.u = shb4[(B) * 4096 + w * 256 + dt * 64 + lsl];         \
            acc[0][dt] = MFMA16(ap0.s, bv.s, acc[0][dt], 0, 0, 0);            \
            acc[1][dt] = MFMA16(ap1.s, bv.s, acc[1][dt], 0, 0, 0);            \
        }                                                                     \
    } while (0)

    // ---- barrier-free pipelined loop ----
    DMA_V(0, 0); LOADK(0, kfA);
    DMA_V(1, 1); LOADK(1, kfB);
    #pragma unroll 1
    for (int tt = 0; tt < 16; tt += 2) {
        __builtin_amdgcn_s_waitcnt(0x0F78);   // vmcnt(8): V(tt)+kf(tt) landed
        __builtin_amdgcn_sched_barrier(0);
        QKEXP(kfA);
        PVS(0);
        __builtin_amdgcn_sched_barrier(0);
        DMA_V(tt + 2, 0); LOADK(tt + 2, kfA);   // buf0 reads completed (lgkm)
        __builtin_amdgcn_s_waitcnt(0x0F78);   // vmcnt(8): V(tt+1)+kf(tt+1)
        __builtin_amdgcn_sched_barrier(0);
        QKEXP(kfB);
        PVS(1);
        __builtin_amdgcn_sched_barrier(0);
        DMA_V(tt + 3, 1); LOADK(tt + 3, kfB);   // tiles wrap via &15 (benign)
    }

    // ---- reduce row-sum partials across the 16 key-lanes of each quad ----
    #pragma unroll
    for (int rt = 0; rt < 2; ++rt)
        #pragma unroll
        for (int r = 0; r < 4; ++r) {
            float v = lsum[rt][r];
            v += __shfl_xor(v, 1);
            v += __shfl_xor(v, 2);
            v += __shfl_xor(v, 4);
            v += __shfl_xor(v, 8);
            lsum[rt][r] = v;   // uniform across the 16 lanes of quad q
        }

    // ---- tree-merge the 8 key-chunk partials within each row-half ----
    __syncthreads();   // drains all outstanding DMA (vmcnt 0) before aliasing
    #pragma unroll 1
    for (int step = 4; step >= 1; step >>= 1) {
        if (kc >= step && kc < 2 * step) {
            float* base = sF + (rh * 4 + (kc - step)) * 2080;
            #pragma unroll
            for (int rt = 0; rt < 2; ++rt) {
                #pragma unroll
                for (int dt = 0; dt < 4; ++dt)
                    #pragma unroll
                    for (int r = 0; r < 4; ++r)
                        base[(rt * 16 + 4 * q + r) * 64 + dt * 16 + i16] = acc[rt][dt][r];
                if (i16 == 0) {
                    #pragma unroll
                    for (int r = 0; r < 4; ++r) base[2048 + rt * 16 + 4 * q + r] = lsum[rt][r];
                }
            }
        }
        __syncthreads();
        if (kc < step) {
            const float* base = sF + (rh * 4 + kc) * 2080;
            #pragma unroll
            for (int rt = 0; rt < 2; ++rt) {
                #pragma unroll
                for (int dt = 0; dt < 4; ++dt)
                    #pragma unroll
                    for (int r = 0; r < 4; ++r)
                        acc[rt][dt][r] += base[(rt * 16 + 4 * q + r) * 64 + dt * 16 + i16];
                #pragma unroll
                for (int r = 0; r < 4; ++r) lsum[rt][r] += base[2048 + rt * 16 + 4 * q + r];
            }
        }
        __syncthreads();
    }

    // ---- kc==0 waves (w=0, w=8) write their row-half's (O,l) partial ----
    if (kc == 0) {
        #pragma unroll
        for (int rt = 0; rt < 2; ++rt) {
            #pragma unroll
            for (int dt = 0; dt < 4; ++dt)
                #pragma unroll
                for (int r = 0; r < 4; ++r) {
                    const int row = qb0 + rh * 32 + rt * 16 + 4 * q + r;
                    Opart[((size_t)kh * 8192 + row) * 64 + dt * 16 + i16] = acc[rt][dt][r];
                }
            if (i16 == 0) {
                #pragma unroll
                for (int r = 0; r < 4; ++r)
                    Lpart[kh * 8192 + qb0 + rh * 32 + rt * 16 + 4 * q + r] = lsum[rt][r];
            }
        }
    }
}

// ---- merge: O = (O0 + O1) / (l0 + l1) ----
__global__ __launch_bounds__(256)
void merge(const float* __restrict__ Opart, const float* __restrict__ Lpart,
           float* __restrict__ Og) {
    const int idx = blockIdx.x * 256 + threadIdx.x;   // 0..131071
    const int row = idx >> 4, seg = idx & 15;
    const float4 a = *(const float4*)(Opart + (size_t)row * 64 + seg * 4);
    const float4 b = *(const float4*)(Opart + ((size_t)8192 + row) * 64 + seg * 4);
    const float inv = 1.0f / (Lpart[row] + Lpart[8192 + row]);
    float4 o;
    o.x = (a.x + b.x) * inv;
    o.y = (a.y + b.y) * inv;
    o.z = (a.z + b.z) * inv;
    o.w = (a.w + b.w) * inv;
    *(float4*)(Og + (size_t)row * 64 + seg * 4) = o;
}

extern "C" void kernel_launch(void* const* d_in, const int* in_sizes, int n_in,
                              void* d_out, int out_size, void* d_ws, size_t ws_size,
                              hipStream_t stream) {
    const float* Q = (const float*)d_in[0];
    const float* K = (const float*)d_in[1];
    const float* V = (const float*)d_in[2];
    float* O = (float*)d_out;
    char* ws = (char*)d_ws;
    uint4* Kb4   = (uint4*)ws;                        // 8 copies x 1 MB
    uint4* Vt4   = (uint4*)(ws + (8 << 20));          // 8 copies x 1 MB
    float* Opart = (float*)(ws + (16 << 20));         // 2 x 8192 x 64 fp32 = 4 MB
    float* Lpart = (float*)(ws + (20 << 20));         // 2 x 8192 fp32
    hipLaunchKernelGGL(prepass, dim3(4096), dim3(256), 0, stream, K, V, Kb4, Vt4);
    hipLaunchKernelGGL(attn_main, dim3(256), dim3(1024), 0, stream, Q, Kb4, Vt4, Opart, Lpart);
    hipLaunchKernelGGL(merge, dim3(512), dim3(256), 0, stream, Opart, Lpart, O);
}

// Round 14
// 97.821 us; speedup vs baseline: 1.1416x; 1.1416x over previous
//
#include <hip/hip_runtime.h>

// Attention 8192x8192, D=DV=64, fp32 in/out.
// R14 = R10 (best: 512thr, 64 rows x 4096 keys, 2-stage QKEXP||PV pipeline,
// trunc P pack) + genuine depth-2 prefetch (3 K/V buffer sets, fully unrolled
// 16 steps: load(T+2) at step T, 2-step load->use distance) + R13's verified
// 8x XCD-local K/Vt copies (frag loads hit the local XCD L2, 8x spread).
// Fixed-offset softmax, (O,l) partials + merge kernel.

#define NQ 8192
#define NK 8192

typedef float f32x4 __attribute__((ext_vector_type(4)));
typedef short short8 __attribute__((ext_vector_type(8)));
union U4 { uint4 u; short8 s; };

#define MFMA16 __builtin_amdgcn_mfma_f32_16x16x32_bf16

// round-to-nearest-even fp32->bf16 pair pack (lo = a) — prepass/Q only
__device__ __forceinline__ unsigned pk2(float a, float b) {
    unsigned ua = __builtin_bit_cast(unsigned, a);
    unsigned ub = __builtin_bit_cast(unsigned, b);
    ua = (ua + 0x7FFFu + ((ua >> 16) & 1u)) >> 16;
    ub = (ub + 0x7FFFu + ((ub >> 16) & 1u)) & 0xFFFF0000u;
    return ua | ub;
}

// 1-op truncation pack: dst = {hi16(b), hi16(a)} (lo = a)
__device__ __forceinline__ unsigned pkt(float a, float b) {
    return __builtin_amdgcn_perm(__builtin_bit_cast(unsigned, b),
                                 __builtin_bit_cast(unsigned, a), 0x07060302u);
}

// ---- prepass: 8 XCD-local copies of fragment-linear bf16 K / Vt ----
// grid 4096: copy = blockIdx%8, j = blockIdx/8: j<256 -> K chunk j, else V.
__global__ __launch_bounds__(256)
void prepass(const float* __restrict__ Kg, const float* __restrict__ Vg,
             uint4* __restrict__ Kb4, uint4* __restrict__ Vt4) {
    __shared__ float ld[64 * 33];
    const int t = threadIdx.x, b = blockIdx.x;
    const int copy = b & 7, j = b >> 3;
    uint4* Kc = Kb4 + (size_t)copy * 65536;
    uint4* Vc = Vt4 + (size_t)copy * 65536;

    if (j < 256) {
        const int kl = t >> 3, dg = t & 7;
        const int e = kl & 1, i16 = kl >> 1, h = dg >> 2, q = dg & 3;
        const float* gp = Kg + (size_t)(j * 32 + kl) * 64 + dg * 8;
        float4 f0 = *(const float4*)gp;
        float4 f1 = *(const float4*)(gp + 4);
        uint4 o = make_uint4(pk2(f0.x, f0.y), pk2(f0.z, f0.w),
                             pk2(f1.x, f1.y), pk2(f1.z, f1.w));
        Kc[(size_t)(j * 4 + e * 2 + h) * 64 + i16 * 4 + q] = o;
    } else {
        const int c = j - 256;
        {
            const int key = t >> 3, dg = t & 7;
            const float* gp = Vg + (size_t)(c * 32 + key) * 64 + dg * 8;
            float4 f0 = *(const float4*)gp;
            float4 f1 = *(const float4*)(gp + 4);
            ld[(dg * 8 + 0) * 33 + key] = f0.x;
            ld[(dg * 8 + 1) * 33 + key] = f0.y;
            ld[(dg * 8 + 2) * 33 + key] = f0.z;
            ld[(dg * 8 + 3) * 33 + key] = f0.w;
            ld[(dg * 8 + 4) * 33 + key] = f1.x;
            ld[(dg * 8 + 5) * 33 + key] = f1.y;
            ld[(dg * 8 + 6) * 33 + key] = f1.z;
            ld[(dg * 8 + 7) * 33 + key] = f1.w;
        }
        __syncthreads();
        {
            const int dim = t >> 2, kq = t & 3;
            const int dt = dim >> 4, i16 = dim & 15;
            float v[8];
            #pragma unroll
            for (int jj = 0; jj < 8; ++jj) v[jj] = ld[dim * 33 + kq * 8 + jj];
            uint4 o = make_uint4(pk2(v[0], v[1]), pk2(v[2], v[3]),
                                 pk2(v[4], v[5]), pk2(v[6], v[7]));
            Vc[(size_t)(c * 4 + dt) * 64 + i16 * 4 + kq] = o;
        }
    }
}

// ---- main kernel: 64 rows x 4096 keys per block, writes (O,l) partials ----
__global__ __launch_bounds__(512, 1)
void attn_main(const float* __restrict__ Qg,
               const uint4* __restrict__ Kb4,
               const uint4* __restrict__ Vt4,
               float* __restrict__ Opart,
               float* __restrict__ Lpart) {
    // LDS: P regions [(w*4+rt)*2+par] x 64 uint4 = 4096 uint4 (64 KB) during
    // the loop; 4 merge regions x 4160 floats (66,560 B) after (post-sync).
    __shared__ uint4 shb4[4160];
    float* sF = (float*)shb4;
    unsigned* shu = (unsigned*)shb4;

    const int t = threadIdx.x, w = t >> 6, lane = t & 63;
    const int q = lane >> 4, i16 = lane & 15;
    const int bid = blockIdx.x;
    const int kh = bid & 1;          // key half 0/1
    const int rg = bid >> 1;         // row group 0..127
    const int qb0 = rg * 64;
    const int lsl = i16 * 4 + q;     // lane-linear slot (0..63)
    const int phase = rg & 15;       // tile-order rotation (16 tiles)
    const uint4* Kb = Kb4 + (size_t)(bid & 7) * 65536;   // XCD-local copy
    const uint4* Vt = Vt4 + (size_t)(bid & 7) * 65536;

    // Q fragments: 4 row-tiles (scale 1/8 * log2 e folded)
    const float SCL = 0.18033688011112042f;
    short8 aq[4][2];
    #pragma unroll
    for (int rt = 0; rt < 4; ++rt) {
        const float* qp = Qg + (size_t)(qb0 + rt * 16 + i16) * 64 + q * 8;
        float4 f0 = *(const float4*)(qp);
        float4 f1 = *(const float4*)(qp + 4);
        U4 u;
        u.u = make_uint4(pk2(f0.x * SCL, f0.y * SCL), pk2(f0.z * SCL, f0.w * SCL),
                         pk2(f1.x * SCL, f1.y * SCL), pk2(f1.z * SCL, f1.w * SCL));
        aq[rt][0] = u.s;
        f0 = *(const float4*)(qp + 32);
        f1 = *(const float4*)(qp + 36);
        u.u = make_uint4(pk2(f0.x * SCL, f0.y * SCL), pk2(f0.z * SCL, f0.w * SCL),
                         pk2(f1.x * SCL, f1.y * SCL), pk2(f1.z * SCL, f1.w * SCL));
        aq[rt][1] = u.s;
    }

    f32x4 acc[4][4];           // O partial accumulators (AGPR), static idx
    float lsum[4][4];          // per-lane row-sum partials (VALU)
    #pragma unroll
    for (int rt = 0; rt < 4; ++rt) {
        #pragma unroll
        for (int dt = 0; dt < 4; ++dt) { acc[rt][dt][0]=0.f; acc[rt][dt][1]=0.f; acc[rt][dt][2]=0.f; acc[rt][dt][3]=0.f; }
        #pragma unroll
        for (int r = 0; r < 4; ++r) lsum[rt][r] = 0.f;
    }

    // P slot indices (layout verified in R2-R13)
    const int tpw = ((i16 >> 2) & 1) + 2 * q + 32 * (i16 >> 3);  // tp = tpw + 8r
    const int pp  = i16 & 3;
    const int tpr = (q & 1) + 2 * ((i16 >> 2) & 3) + 8 * (i16 & 3) + 32 * (q >> 1);

    uint4 kf0[4], vf0[4], kf1[4], vf1[4], kf2[4], vf2[4];

    // chunk base for wave w in tile TT (8 chunks/tile, 16 tiles, key-half kh)
#define LOAD_T(TT, KD, VD)                                                           \
    do {                                                                             \
        const int cb = ((kh << 7) + ((((TT) + phase) & 15) * 8 + w)) * 4;            \
        _Pragma("unroll")                                                            \
        for (int eh = 0; eh < 4; ++eh)                                               \
            (KD)[eh] = Kb[(size_t)(cb + eh) * 64 + lsl];                             \
        _Pragma("unroll")                                                            \
        for (int dt = 0; dt < 4; ++dt)                                               \
            (VD)[dt] = Vt[(size_t)(cb + dt) * 64 + lsl];                             \
    } while (0)

    // stage 1: QK^T -> exp2 -> truncation-pack P into parity region PAR
#define QKEXP(KD, PAR)                                                               \
    do {                                                                             \
        U4 u0, u1, u2, u3;                                                           \
        u0.u = (KD)[0]; u1.u = (KD)[1]; u2.u = (KD)[2]; u3.u = (KD)[3];              \
        _Pragma("unroll")                                                            \
        for (int rt = 0; rt < 4; ++rt) {                                             \
            f32x4 s0, s1;                                                            \
            s0[0]=-16.f; s0[1]=-16.f; s0[2]=-16.f; s0[3]=-16.f;                      \
            s1[0]=-16.f; s1[1]=-16.f; s1[2]=-16.f; s1[3]=-16.f;                      \
            s0 = MFMA16(aq[rt][0], u0.s, s0, 0, 0, 0);                               \
            s0 = MFMA16(aq[rt][1], u1.s, s0, 0, 0, 0);                               \
            s1 = MFMA16(aq[rt][0], u2.s, s1, 0, 0, 0);                               \
            s1 = MFMA16(aq[rt][1], u3.s, s1, 0, 0, 0);                               \
            const int rbase = (((w * 4 + rt) * 2) + (PAR)) * 256;                    \
            _Pragma("unroll")                                                        \
            for (int r = 0; r < 4; ++r) {                                            \
                float p0 = __builtin_amdgcn_exp2f(s0[r]);                            \
                float p1 = __builtin_amdgcn_exp2f(s1[r]);                            \
                lsum[rt][r] += p0;                                                   \
                lsum[rt][r] += p1;                                                   \
                shu[rbase + (tpw + 8 * r) * 4 + pp] = pkt(p0, p1);                   \
            }                                                                        \
        }                                                                            \
    } while (0)

    // stage 2: read P A-frags from parity region PAR, PV MFMA with VD
#define PVS(VD, PAR)                                                                 \
    do {                                                                             \
        U4 ap[4];                                                                    \
        _Pragma("unroll")                                                            \
        for (int rt = 0; rt < 4; ++rt)                                               \
            ap[rt].u = shb4[(((w * 4 + rt) * 2) + (PAR)) * 64 + tpr];                \
        _Pragma("unroll")                                                            \
        for (int dt = 0; dt < 4; ++dt) {                                             \
            U4 bv; bv.u = (VD)[dt];                                                  \
            _Pragma("unroll")                                                        \
            for (int rt = 0; rt < 4; ++rt)                                           \
                acc[rt][dt] = MFMA16(ap[rt].s, bv.s, acc[rt][dt], 0, 0, 0);          \
        }                                                                            \
    } while (0)

#define SB __builtin_amdgcn_sched_barrier(0)

    // ---- fully-unrolled 16-step loop, depth-2 prefetch, 3 buffer sets ----
    LOAD_T(0, kf0, vf0);
    LOAD_T(1, kf1, vf1);
    QKEXP(kf0, 0);                LOAD_T(2,  kf2, vf2); SB;   // T=0
    QKEXP(kf1, 1); PVS(vf0, 0);   LOAD_T(3,  kf0, vf0); SB;   // T=1
    QKEXP(kf2, 0); PVS(vf1, 1);   LOAD_T(4,  kf1, vf1); SB;   // T=2
    QKEXP(kf0, 1); PVS(vf2, 0);   LOAD_T(5,  kf2, vf2); SB;   // T=3
    QKEXP(kf1, 0); PVS(vf0, 1);   LOAD_T(6,  kf0, vf0); SB;   // T=4
    QKEXP(kf2, 1); PVS(vf1, 0);   LOAD_T(7,  kf1, vf1); SB;   // T=5
    QKEXP(kf0, 0); PVS(vf2, 1);   LOAD_T(8,  kf2, vf2); SB;   // T=6
    QKEXP(kf1, 1); PVS(vf0, 0);   LOAD_T(9,  kf0, vf0); SB;   // T=7
    QKEXP(kf2, 0); PVS(vf1, 1);   LOAD_T(10, kf1, vf1); SB;   // T=8
    QKEXP(kf0, 1); PVS(vf2, 0);   LOAD_T(11, kf2, vf2); SB;   // T=9
    QKEXP(kf1, 0); PVS(vf0, 1);   LOAD_T(12, kf0, vf0); SB;   // T=10
    QKEXP(kf2, 1); PVS(vf1, 0);   LOAD_T(13, kf1, vf1); SB;   // T=11
    QKEXP(kf0, 0); PVS(vf2, 1);   LOAD_T(14, kf2, vf2); SB;   // T=12
    QKEXP(kf1, 1); PVS(vf0, 0);   LOAD_T(15, kf0, vf0); SB;   // T=13
    QKEXP(kf2, 0); PVS(vf1, 1);                         SB;   // T=14
    QKEXP(kf0, 1); PVS(vf2, 0);                         SB;   // T=15
    PVS(vf0, 1);                                              // PV(15)

    // ---- reduce row-sum partials across the 16 key-lanes of each quad ----
    #pragma unroll
    for (int rt = 0; rt < 4; ++rt)
        #pragma unroll
        for (int r = 0; r < 4; ++r) {
            float v = lsum[rt][r];
            v += __shfl_xor(v, 1);
            v += __shfl_xor(v, 2);
            v += __shfl_xor(v, 4);
            v += __shfl_xor(v, 8);
            lsum[rt][r] = v;   // uniform across the 16 lanes of quad q
        }

    // ---- tree-merge the 8 key-chunk partials (regions: 4160 floats) ----
    __syncthreads();
    #pragma unroll 1
    for (int step = 4; step >= 1; step >>= 1) {
        if (w >= step && w < 2 * step) {
            float* base = sF + (w - step) * 4160;
            #pragma unroll
            for (int rt = 0; rt < 4; ++rt) {
                #pragma unroll
                for (int dt = 0; dt < 4; ++dt)
                    #pragma unroll
                    for (int r = 0; r < 4; ++r)
                        base[(rt * 16 + 4 * q + r) * 64 + dt * 16 + i16] = acc[rt][dt][r];
                if (i16 == 0) {
                    #pragma unroll
                    for (int r = 0; r < 4; ++r) base[4096 + rt * 16 + 4 * q + r] = lsum[rt][r];
                }
            }
        }
        __syncthreads();
        if (w < step) {
            const float* base = sF + w * 4160;
            #pragma unroll
            for (int rt = 0; rt < 4; ++rt) {
                #pragma unroll
                for (int dt = 0; dt < 4; ++dt)
                    #pragma unroll
                    for (int r = 0; r < 4; ++r)
                        acc[rt][dt][r] += base[(rt * 16 + 4 * q + r) * 64 + dt * 16 + i16];
                #pragma unroll
                for (int r = 0; r < 4; ++r) lsum[rt][r] += base[4096 + rt * 16 + 4 * q + r];
            }
        }
        __syncthreads();
    }

    // ---- wave 0 writes the block's (O,l) partial to global ----
    if (w == 0) {
        #pragma unroll
        for (int rt = 0; rt < 4; ++rt) {
            #pragma unroll
            for (int dt = 0; dt < 4; ++dt)
                #pragma unroll
                for (int r = 0; r < 4; ++r) {
                    const int row = qb0 + rt * 16 + 4 * q + r;
                    Opart[((size_t)kh * 8192 + row) * 64 + dt * 16 + i16] = acc[rt][dt][r];
                }
            if (i16 == 0) {
                #pragma unroll
                for (int r = 0; r < 4; ++r)
                    Lpart[kh * 8192 + qb0 + rt * 16 + 4 * q + r] = lsum[rt][r];
            }
        }
    }
}

// ---- merge: O = (O0 + O1) / (l0 + l1) ----
__global__ __launch_bounds__(256)
void merge(const float* __restrict__ Opart, const float* __restrict__ Lpart,
           float* __restrict__ Og) {
    const int idx = blockIdx.x * 256 + threadIdx.x;   // 0..131071
    const int row = idx >> 4, seg = idx & 15;
    const float4 a = *(const float4*)(Opart + (size_t)row * 64 + seg * 4);
    const float4 b = *(const float4*)(Opart + ((size_t)8192 + row) * 64 + seg * 4);
    const float inv = 1.0f / (Lpart[row] + Lpart[8192 + row]);
    float4 o;
    o.x = (a.x + b.x) * inv;
    o.y = (a.y + b.y) * inv;
    o.z = (a.z + b.z) * inv;
    o.w = (a.w + b.w) * inv;
    *(float4*)(Og + (size_t)row * 64 + seg * 4) = o;
}

extern "C" void kernel_launch(void* const* d_in, const int* in_sizes, int n_in,
                              void* d_out, int out_size, void* d_ws, size_t ws_size,
                              hipStream_t stream) {
    const float* Q = (const float*)d_in[0];
    const float* K = (const float*)d_in[1];
    const float* V = (const float*)d_in[2];
    float* O = (float*)d_out;
    char* ws = (char*)d_ws;
    uint4* Kb4   = (uint4*)ws;                        // 8 copies x 1 MB
    uint4* Vt4   = (uint4*)(ws + (8 << 20));          // 8 copies x 1 MB
    float* Opart = (float*)(ws + (16 << 20));         // 2 x 8192 x 64 fp32 = 4 MB
    float* Lpart = (float*)(ws + (20 << 20));         // 2 x 8192 fp32
    hipLaunchKernelGGL(prepass, dim3(4096), dim3(256), 0, stream, K, V, Kb4, Vt4);
    hipLaunchKernelGGL(attn_main, dim3(256), dim3(512), 0, stream, Q, Kb4, Vt4, Opart, Lpart);
    hipLaunchKernelGGL(merge, dim3(512), dim3(256), 0, stream, Opart, Lpart, O);
}